// Round 3
// baseline (49.015 us; speedup 1.0000x reference)
//
#include <hip/hip_runtime.h>

// out[i,j] = exp((s1[i]-s2[j])^2) * gamma,  s1=rowsum(input1), s2=rowsum(input2)
// Single fused kernel. Each block: ROWS x 1024 output tile.
//   - s2 for the block's 1024 columns: 4 values per thread, kept in registers.
//   - s1 for the block's ROWS rows: first ROWS threads compute into LDS.
//   - 32 nontemporal 16B stores per thread (streaming output, never re-read).

#define N1 8192
#define N2 8192
#define D  8
#define ROWS 32

typedef float f32x4 __attribute__((ext_vector_type(4)));

__device__ __forceinline__ float rowsum8(const float* __restrict__ p) {
    const f32x4* q = reinterpret_cast<const f32x4*>(p);
    f32x4 a = q[0];
    f32x4 b = q[1];
    return ((a.x + a.y) + (a.z + a.w)) + ((b.x + b.y) + (b.z + b.w));
}

__global__ void __launch_bounds__(256)
rbf_fused_kernel(const float* __restrict__ in1,
                 const float* __restrict__ in2,
                 const float* __restrict__ gamma_p,
                 f32x4* __restrict__ out) {
    const int cb = blockIdx.x;   // column chunk (1024 cols)
    const int rb = blockIdx.y;   // row group (ROWS rows)
    const int t  = threadIdx.x;

    __shared__ float s1s[ROWS];

    // s2 for my 4 columns (registers, fixed across all rows)
    const int col0 = cb * 1024 + t * 4;
    float s20 = rowsum8(in2 + (size_t)(col0 + 0) * D);
    float s21 = rowsum8(in2 + (size_t)(col0 + 1) * D);
    float s22 = rowsum8(in2 + (size_t)(col0 + 2) * D);
    float s23 = rowsum8(in2 + (size_t)(col0 + 3) * D);

    // s1 for this block's rows
    if (t < ROWS) {
        s1s[t] = rowsum8(in1 + (size_t)(rb * ROWS + t) * D);
    }
    const float g = gamma_p[0];
    __syncthreads();

    f32x4* __restrict__ orow = out + (size_t)(rb * ROWS) * (N2 / 4) + cb * 256 + t;

    #pragma unroll 4
    for (int r = 0; r < ROWS; ++r) {
        const float s1 = s1s[r];           // same addr across wave -> LDS broadcast
        float d0 = s1 - s20;
        float d1 = s1 - s21;
        float d2 = s1 - s22;
        float d3 = s1 - s23;
        f32x4 v;
        v.x = __expf(d0 * d0) * g;
        v.y = __expf(d1 * d1) * g;
        v.z = __expf(d2 * d2) * g;
        v.w = __expf(d3 * d3) * g;
        __builtin_nontemporal_store(v, orow);
        orow += N2 / 4;
    }
}

extern "C" void kernel_launch(void* const* d_in, const int* in_sizes, int n_in,
                              void* d_out, int out_size, void* d_ws, size_t ws_size,
                              hipStream_t stream) {
    const float* in1     = (const float*)d_in[0];
    const float* in2     = (const float*)d_in[1];
    const float* gamma_p = (const float*)d_in[2];
    f32x4* out = (f32x4*)d_out;

    dim3 block(256);
    dim3 grid(N2 / 1024, N1 / ROWS);   // (8, 256) = 2048 blocks
    rbf_fused_kernel<<<grid, block, 0, stream>>>(in1, in2, gamma_p, out);
}